// Round 29
// baseline (174.562 us; speedup 1.0000x reference)
//
#include <hip/hip_runtime.h>

// TransformerConvolution (graph attention with per-edge keys), MI355X gfx950.
// Rewrite: q_j . (edge_ij @ We_k) == edge_ij . (We_k^T q_j) = edge . qe_j
// -> 16x less per-edge work, no 268MB edge_k intermediate.
// Memory floor: one streaming read of edge_fts (134 MB) ~ 21 us at 6.3 TB/s.
//
// ROUND-29 FIX: the reference output dtype is FLOAT32 (reference is f32
// end-to-end). Rounds 2-28 wrote packed bf16 into the f32 buffer -> validator
// saw reinterpreted garbage + untouched zeros = absmax 1.0078 (max|ref|),
// byte-identical to the stub. Proven by round-28 probes:
//   KL_ORANGE size=524288 (= out_size*4), KL_RB1 writes land,
//   KL_RB2 = our bf16 pairs packed 2-per-f32-word.
// Store f32. All diagnostics removed (graph-capture-clean).

__device__ inline float guard_relu(float x) {
    if (x != x) return 0.0f;
    return fmaxf(x, 0.0f);
}

// ---------- Kernel 1: z@{Wq,Wk,Wv}, qe = We_k^T q  (256 blocks x 256) ------
__global__ void tc25_prep(
    const float* node, const float* hidden,
    const float* Wq, const float* Wk, const float* Wv, const float* Wek,
    float* qbuf, float* kbuf, float* vbuf, float* qebuf)
{
    __shared__ float z[4][128];
    __shared__ float qs[4][128];
    const int t = threadIdx.x;
    const int r0 = blockIdx.x * 4;            // global row = b*512 + n

    for (int kk = 0; kk < 2; ++kk) {
        int idx = t + kk * 256;               // 0..511
        int r = idx >> 7, c = idx & 127;
        int row = r0 + r;
        z[r][c] = (c < 64) ? node[row * 64 + c] : hidden[row * 64 + (c - 64)];
    }
    __syncthreads();

    const int o  = t & 127;
    const int rh = t >> 7;                    // rows rh and rh+2
    float aq0 = 0.f, aq1 = 0.f, ak0 = 0.f, ak1 = 0.f, av0 = 0.f, av1 = 0.f;
    for (int c = 0; c < 128; ++c) {
        float wq = Wq[c * 128 + o], wk = Wk[c * 128 + o], wv = Wv[c * 128 + o];
        float z0 = z[rh][c], z1 = z[rh + 2][c];
        aq0 = fmaf(z0, wq, aq0); aq1 = fmaf(z1, wq, aq1);
        ak0 = fmaf(z0, wk, ak0); ak1 = fmaf(z1, wk, ak1);
        av0 = fmaf(z0, wv, av0); av1 = fmaf(z1, wv, av1);
    }
    {
        int row0 = r0 + rh, row1 = r0 + rh + 2;
        qbuf[row0 * 128 + o] = aq0; qbuf[row1 * 128 + o] = aq1;
        kbuf[row0 * 128 + o] = ak0; kbuf[row1 * 128 + o] = ak1;
        vbuf[row0 * 128 + o] = av0; vbuf[row1 * 128 + o] = av1;
        qs[rh][o] = aq0; qs[rh + 2][o] = aq1;
    }
    __syncthreads();

    // qe[row][h][c] = sum_d q[row][h*16+d] * Wek[c*128 + h*16 + d]
    for (int kk = 0; kk < 2; ++kk) {
        int hc = t + kk * 256;                // 0..511
        int h = hc >> 6, c = hc & 63;
        for (int r = 0; r < 4; ++r) {
            float s = 0.f;
            for (int d = 0; d < 16; ++d)
                s = fmaf(qs[r][h * 16 + d], Wek[c * 128 + h * 16 + d], s);
            qebuf[((r0 + r) * 8 + h) * 64 + c] = s;
        }
    }
}

// ---------- Kernel 2: full-j attention, normalized out (512 blocks x 256) --
__global__ void tc25_attn(
    const float* edge, const float* adj,
    const float* qbuf, const float* kbuf, const float* vbuf,
    const float* qebuf, float* aout)
{
    __shared__ float qls[2][128];
    __shared__ float els[2][8][132];
    const int t  = threadIdx.x;
    const int b  = blockIdx.x >> 8;
    const int i0 = (blockIdx.x & 255) * 2;
    const int ia = t & 1;                     // score phase: row
    const int ja = t >> 1;                    // score phase: j in tile (0..127)
    const int ip = t >> 7;                    // PV phase: row
    const int o  = t & 127;                   // PV phase: outdim (h*16+d)
    const int hB = o >> 4;

    qls[t >> 7][t & 127] = qbuf[(b * 512 + i0 + (t >> 7)) * 128 + (t & 127)];
    __syncthreads();

    float acc = 0.f, dacc = 0.f;

    for (int jt = 0; jt < 4; ++jt) {
        const int j = jt * 128 + ja;
        const float* Erow  = edge  + ((size_t)(b * 512 + i0 + ia) * 512 + j) * 64;
        const float* qerow = qebuf + (size_t)(b * 512 + j) * 512;
        float s0 = 0.f, s1 = 0.f, s2 = 0.f, s3 = 0.f;
        float s4 = 0.f, s5 = 0.f, s6 = 0.f, s7 = 0.f;
        for (int c = 0; c < 64; ++c) {
            float e = Erow[c];
            s0 = fmaf(e, qerow[0 * 64 + c], s0);
            s1 = fmaf(e, qerow[1 * 64 + c], s1);
            s2 = fmaf(e, qerow[2 * 64 + c], s2);
            s3 = fmaf(e, qerow[3 * 64 + c], s3);
            s4 = fmaf(e, qerow[4 * 64 + c], s4);
            s5 = fmaf(e, qerow[5 * 64 + c], s5);
            s6 = fmaf(e, qerow[6 * 64 + c], s6);
            s7 = fmaf(e, qerow[7 * 64 + c], s7);
        }
        float sh[8] = {s0, s1, s2, s3, s4, s5, s6, s7};
        const float* krow = kbuf + (size_t)(b * 512 + j) * 128;
        for (int h = 0; h < 8; ++h) {
            float qk = 0.f;
            for (int d = 0; d < 16; ++d)
                qk = fmaf(krow[h * 16 + d], qls[ia][h * 16 + d], qk);
            sh[h] += qk;
        }
        const float am = adj[(size_t)(b * 512 + i0 + ia) * 512 + j];
        __syncthreads();                      // prior-tile PV readers done
        for (int h = 0; h < 8; ++h)
            els[ia][h][ja] = am * __expf(sh[h] * 0.25f);
        __syncthreads();

        const float* vbase = vbuf + (size_t)(b * 512 + jt * 128) * 128 + o;
        for (int jl = 0; jl < 128; ++jl) {
            float e = els[ip][hB][jl];
            acc = fmaf(e, vbase[jl * 128], acc);
            dacc += e;
        }
    }
    aout[(size_t)(b * 512 + i0 + ip) * 128 + o] = acc / dacc;   // self-loops -> dacc>0
}

// ---------- Kernel 3: Wo + FFN, f32 store (256 blocks x 256) ---------------
__global__ void tc25_post(
    const float* aout, const float* Wo, const float* W1,
    const float* b1f, const float* W2, const float* b2f,
    float* __restrict__ out)
{
    __shared__ float a[4][128];
    __shared__ float y[4][128];
    const int t = threadIdx.x;
    const int o = t & 127, rh = t >> 7;
    const int r0 = blockIdx.x * 4;

    a[rh][o]     = aout[(r0 + rh) * 128 + o];
    a[rh + 2][o] = aout[(r0 + rh + 2) * 128 + o];
    __syncthreads();

    float acc0 = 0.f, acc1 = 0.f;
    for (int c = 0; c < 128; ++c) {
        float w = Wo[c * 128 + o];
        acc0 = fmaf(a[rh][c], w, acc0);
        acc1 = fmaf(a[rh + 2][c], w, acc1);
    }
    y[rh][o] = acc0; y[rh + 2][o] = acc1;
    __syncthreads();

    acc0 = 0.f; acc1 = 0.f;
    for (int c = 0; c < 128; ++c) {
        float w = W1[c * 128 + o];
        acc0 = fmaf(y[rh][c], w, acc0);
        acc1 = fmaf(y[rh + 2][c], w, acc1);
    }
    float bb = b1f[o];
    __syncthreads();
    a[rh][o]     = guard_relu(acc0 + bb);
    a[rh + 2][o] = guard_relu(acc1 + bb);
    __syncthreads();

    acc0 = 0.f; acc1 = 0.f;
    for (int c = 0; c < 128; ++c) {
        float w = W2[c * 128 + o];
        acc0 = fmaf(a[rh][c], w, acc0);
        acc1 = fmaf(a[rh + 2][c], w, acc1);
    }
    float bb2 = b2f[o];
    int row0 = r0 + rh, row1 = r0 + rh + 2;
    out[row0 * 128 + o] = guard_relu(acc0 + bb2);   // FLOAT32 store
    out[row1 * 128 + o] = guard_relu(acc1 + bb2);
}

extern "C" void kernel_launch(void* const* d_in, const int* in_sizes, int n_in,
                              void* d_out, int out_size, void* d_ws, size_t ws_size,
                              hipStream_t stream) {
    (void)in_sizes; (void)n_in; (void)out_size; (void)ws_size;

    const float* node   = (const float*)d_in[0];
    const float* edge   = (const float*)d_in[1];
    const float* hidden = (const float*)d_in[3];   // d_in[2] = graph_fts, unused
    const float* adj    = (const float*)d_in[4];
    const float* Wq     = (const float*)d_in[5];
    const float* Wk     = (const float*)d_in[6];
    const float* Wv     = (const float*)d_in[7];
    const float* Wo     = (const float*)d_in[8];
    const float* Wek    = (const float*)d_in[9];
    const float* W1     = (const float*)d_in[10];
    const float* b1f    = (const float*)d_in[11];
    const float* W2     = (const float*)d_in[12];
    const float* b2f    = (const float*)d_in[13];
    float* out = (float*)d_out;                    // reference output is f32

    float* ws    = (float*)d_ws;
    float* qbuf  = ws;                 // 131072 f32
    float* kbuf  = qbuf  + 131072;     // 131072
    float* vbuf  = kbuf  + 131072;     // 131072
    float* qebuf = vbuf  + 131072;     // 524288  qe[b][j][h][c]
    float* abuf  = qebuf + 524288;     // 131072
    // total 4.0 MiB workspace (all regions fully written before read)

    tc25_prep<<<256, 256, 0, stream>>>(node, hidden, Wq, Wk, Wv, Wek,
                                       qbuf, kbuf, vbuf, qebuf);
    tc25_attn<<<512, 256, 0, stream>>>(edge, adj, qbuf, kbuf, vbuf, qebuf, abuf);
    tc25_post<<<256, 256, 0, stream>>>(abuf, Wo, W1, b1f, W2, b2f, out);
}